// Round 11
// baseline (5323.302 us; speedup 1.0000x reference)
//
#include <hip/hip_runtime.h>
#include <hip/hip_bf16.h>
#include <stdint.h>

// Problem constants (from setup_inputs)
#define N_TOK 8192
#define C_DIM 2048
#define E_NUM 8
#define H_DIM 1408
#define HS_DIM 2816
#define NRPAD 18432      // 16384 routed slots + per-expert padding to 256
#define MAXT256 72       // 64 full tiles + 8 partial

typedef unsigned short u16;
typedef float f32x4_t __attribute__((ext_vector_type(4)));
typedef short bf16x8_t __attribute__((ext_vector_type(8)));

__device__ __forceinline__ u16 f2bf(float f) {
  union { float f; uint32_t u; } c; c.f = f;
  uint32_t u = c.u;
  return (u16)((u + 0x7fffu + ((u >> 16) & 1u)) >> 16);
}
__device__ __forceinline__ float bf2f(u16 b) {
  union { uint32_t u; float f; } c; c.u = ((uint32_t)b) << 16;
  return c.f;
}

__device__ __forceinline__ void async_copy16(const u16* gsrc, u16* ldst) {
  __builtin_amdgcn_global_load_lds(
      (const __attribute__((address_space(1))) void*)gsrc,
      (__attribute__((address_space(3))) void*)ldst, 16, 0, 0);
}

#define BARRIER() asm volatile("s_barrier" ::: "memory")
#define WAITV0()  asm volatile("s_waitcnt vmcnt(0)" ::: "memory")
#define SCHED0()  __builtin_amdgcn_sched_barrier(0)

// ---------------- fp32 -> bf16 conversion ----------------
__global__ __launch_bounds__(256) void cvt_bf16_kernel(
    const float* __restrict__ in, u16* __restrict__ out, int n4) {
  int i = blockIdx.x * blockDim.x + threadIdx.x;
  int stride = gridDim.x * blockDim.x;
  for (; i < n4; i += stride) {
    float4 v = ((const float4*)in)[i];
    ushort4 u;
    u.x = f2bf(v.x); u.y = f2bf(v.y); u.z = f2bf(v.z); u.w = f2bf(v.w);
    ((ushort4*)out)[i] = u;
  }
}

// ---------------- gate: fp32 scores, top-2, renorm weights ----------------
__global__ __launch_bounds__(256) void gate_topk_kernel(
    const float* __restrict__ x, const float* __restrict__ gw,
    const float* __restrict__ gbias,
    int* __restrict__ tok_e, float* __restrict__ tok_w, int* __restrict__ counts) {
  int n = blockIdx.x;
  const float* xr = x + (size_t)n * C_DIM;
  int t = threadIdx.x;
  float acc[E_NUM];
#pragma unroll
  for (int e = 0; e < E_NUM; ++e) acc[e] = 0.f;
  for (int k0 = t * 4; k0 < C_DIM; k0 += 1024) {
    float4 xv = *(const float4*)(xr + k0);
#pragma unroll
    for (int e = 0; e < E_NUM; ++e) {
      float4 gv = *(const float4*)(gw + e * C_DIM + k0);
      acc[e] += xv.x * gv.x + xv.y * gv.y + xv.z * gv.z + xv.w * gv.w;
    }
  }
#pragma unroll
  for (int e = 0; e < E_NUM; ++e)
    for (int off = 32; off > 0; off >>= 1) acc[e] += __shfl_xor(acc[e], off, 64);
  __shared__ float sred[4][E_NUM];
  int wid = t >> 6, lane = t & 63;
  if (lane == 0) {
#pragma unroll
    for (int e = 0; e < E_NUM; ++e) sred[wid][e] = acc[e];
  }
  __syncthreads();
  if (t == 0) {
    float sc[E_NUM];
#pragma unroll
    for (int e = 0; e < E_NUM; ++e) {
      float s = sred[0][e] + sred[1][e] + sred[2][e] + sred[3][e];
      sc[e] = 1.f / (1.f + expf(-s));
    }
    int e0 = 0; float k0v = sc[0] + gbias[0];
    for (int e = 1; e < E_NUM; ++e) {
      float ke = sc[e] + gbias[e];
      if (ke > k0v) { k0v = ke; e0 = e; }
    }
    int e1 = -1; float k1v = -1e30f;
    for (int e = 0; e < E_NUM; ++e) {
      if (e == e0) continue;
      float ke = sc[e] + gbias[e];
      if (ke > k1v) { k1v = ke; e1 = e; }
    }
    float w0 = sc[e0], w1 = sc[e1];
    float s = w0 + w1;
    w0 /= s; w1 /= s;
    tok_e[2 * n] = e0; tok_e[2 * n + 1] = e1;
    tok_w[2 * n] = w0; tok_w[2 * n + 1] = w1;
    atomicAdd(&counts[e0], 1);
    atomicAdd(&counts[e1], 1);
  }
}

// ---------------- routing scan: 256-padded offsets + tile table ----------------
__global__ void scan_route_kernel(const int* __restrict__ counts,
                                  int* __restrict__ off_pad,
                                  int* __restrict__ tile_e, int* __restrict__ tile_s0,
                                  int* __restrict__ ntiles) {
  if (threadIdx.x == 0 && blockIdx.x == 0) {
    int off = 0, t = 0;
    for (int e = 0; e < E_NUM; ++e) {
      off_pad[e] = off;
      int tiles = (counts[e] + 255) >> 8;
      for (int i = 0; i < tiles; ++i) { tile_e[t] = e; tile_s0[t] = off + i * 256; ++t; }
      off += tiles * 256;
    }
    *ntiles = t;
  }
}

__global__ __launch_bounds__(256) void build_slots_kernel(
    const int* __restrict__ tok_e, const int* __restrict__ off_pad,
    int* __restrict__ cursor, int* __restrict__ slot_tok, int* __restrict__ slot_of) {
  int n = blockIdx.x * blockDim.x + threadIdx.x;
  if (n >= N_TOK) return;
#pragma unroll
  for (int j = 0; j < 2; ++j) {
    int e = tok_e[2 * n + j];
    int pos = atomicAdd(&cursor[e], 1);
    int s = off_pad[e] + pos;
    slot_tok[s] = n;
    slot_of[2 * n + j] = s;
  }
}

// ---------------- 256x256 double-buffered BK=32 bf16 GEMM, 2 blocks/CU -------
// 512 threads = 8 waves (2 wm x 4 wn); per-wave output 128x64, acc[8][4].
// LDS: 2 buffers x (A[256][32] + B[256][32]) bf16 = 64 KiB -> TWO blocks/CU
// (__launch_bounds__(512,4)); the co-resident block's MFMA phases cover this
// block's vmcnt/barrier stalls (cross-block, no shared barriers) -- the m114
// implicit-overlap mechanism that the 1-block/CU (96-128 KiB) variants lost.
// Per 32-K step: stage A(s+1) top, B(s+1) mid; 2 MFMA clusters; end-of-step
// vmcnt(0)+barrier publishes buf(s+1). WAR: nxt writes issue only after the
// barrier sealing step s-1's reads.
// T2 swizzle: col-group ^= (row>>1)&3 via pre-swizzled global src + XOR read.
// FUSE: B tile rows interleave 16-row sil/mul blocks so acc[m][2j]=g,
// acc[m][2j+1]=u share a lane; epilogue writes silu(g)*u (128 h cols/block).
template <bool GATHER, bool ROUTE, bool F32OUT, bool FUSE>
__global__ __launch_bounds__(512, 4) void gemm256(
    const u16* __restrict__ A, const u16* __restrict__ B,
    void* __restrict__ Out, int ldo, int K, int nbn,
    const int* __restrict__ tile_e, const int* __restrict__ tile_s0,
    const int* __restrict__ ntiles, const int* __restrict__ slot_tok,
    long estride, int silbase, int mulbase) {
  // XCD-contiguous chunks; within a chunk, 4-mt bands swept across nt.
  const int chunk = gridDim.x >> 3;
  const int orig = blockIdx.x;
  const int l = (orig & 7) * chunk + (orig >> 3);
  const int bandsz = nbn << 2;
  const int band = l / bandsz;
  const int rem = l - band * bandsz;
  const int nt = rem >> 2;
  const int mt = (band << 2) + (rem & 3);
  if (ROUTE) { if (mt >= *ntiles) return; }
  const int m0 = ROUTE ? tile_s0[mt] : (mt << 8);
  const u16* Bb = B + (ROUTE ? (size_t)tile_e[mt] * (size_t)estride : 0);
  const int n0 = nt << 8;   // acc-col base (unfused)
  const int h0 = nt << 7;   // fused h-col base

  __shared__ u16 lds[32768];   // 2 x (A[256][32] + B[256][32]) = 64 KiB

  const int t = threadIdx.x;
  const int w = t >> 6, lane = t & 63;
  const int wst = w << 9;                  // wave slice within a 4096-u16 issue
  // staging source pointers (pre-swizzled global col-group)
  const int rt2 = t >> 2;                  // staged row 0..127
  const int coff = (((t & 3) ^ ((rt2 >> 1) & 3)) << 3);
  const u16* aS[2]; const u16* bS[2];
#pragma unroll
  for (int j = 0; j < 2; ++j) {
    int r = (j << 7) + rt2;
    int arow = GATHER ? slot_tok[m0 + r] : (m0 + r);
    aS[j] = A + (size_t)arow * K + coff;
    int grow;
    if (FUSE) {
      grow = (((r >> 4) & 1) ? mulbase : silbase) + h0 + ((r >> 5) << 4) + (r & 15);
    } else {
      grow = n0 + r;
    }
    bS[j] = Bb + (size_t)grow * K + coff;
  }

  const int wm = w >> 2, wn = w & 3;
  const int fr = lane & 15, kq = lane >> 4;
  const int swz = ((kq ^ ((fr >> 1) & 3)) << 3);   // u16 col offset in 32-u16 row

  f32x4_t acc[8][4];
  f32x4_t zero4 = {0.f, 0.f, 0.f, 0.f};
#pragma unroll
  for (int m = 0; m < 8; ++m)
#pragma unroll
    for (int n = 0; n < 4; ++n) acc[m][n] = zero4;

#define STG_A(NB, KST) \
  async_copy16(aS[0] + (KST), &lds[(NB) + wst]); \
  async_copy16(aS[1] + (KST), &lds[(NB) + 4096 + wst]);
#define STG_B(NB, KST) \
  async_copy16(bS[0] + (KST), &lds[(NB) + 8192 + wst]); \
  async_copy16(bS[1] + (KST), &lds[(NB) + 8192 + 4096 + wst]);
#define LDA_(DST, MOFF) \
  _Pragma("unroll") \
  for (int m = 0; m < 4; ++m) { \
    int row = (wm << 7) + (MOFF) + (m << 4) + fr; \
    DST[m] = *(const bf16x8_t*)&lds[cur + (row << 5) + swz]; \
  }
#define LDB_() \
  _Pragma("unroll") \
  for (int n = 0; n < 4; ++n) { \
    int row = (wn << 6) + (n << 4) + fr; \
    bfr[n] = *(const bf16x8_t*)&lds[cur + 8192 + (row << 5) + swz]; \
  }
#define MFMA16(AB, AFR) \
  __builtin_amdgcn_s_setprio(1); \
  _Pragma("unroll") \
  for (int m = 0; m < 4; ++m) \
    _Pragma("unroll") \
    for (int n = 0; n < 4; ++n) \
      acc[(AB) + m][n] = __builtin_amdgcn_mfma_f32_16x16x32_bf16( \
          AFR[m], bfr[n], acc[(AB) + m][n], 0, 0, 0); \
  __builtin_amdgcn_s_setprio(0);

  const int NS = K >> 5;
  // prologue: stage step 0 -> buf0
  STG_A(0, 0); STG_B(0, 0);
  WAITV0(); SCHED0();
  BARRIER();

  for (int s = 0; s < NS; ++s) {
    const int cur = (s & 1) << 14;
    const int nxt = ((s + 1) & 1) << 14;
    const int kst = (s + 1 < NS ? (s + 1) : s) << 5;   // last step: junk re-stage
    bf16x8_t afr[4], afr2[4], bfr[4];

    // P1: m-lo cluster; stage A(s+1)
    STG_A(nxt, kst);
    LDB_(); LDA_(afr, 0);
    BARRIER();
    MFMA16(0, afr);
    BARRIER();
    // P2: m-hi cluster; stage B(s+1)
    LDA_(afr2, 64);
    STG_B(nxt, kst);
    BARRIER();
    MFMA16(4, afr2);
    WAITV0(); SCHED0();   // step-(s+1) loads landed
    BARRIER();            // publish buf(s+1); seals cur for overwrite at s+1
  }

  // epilogue
#pragma unroll
  for (int mf = 0; mf < 8; ++mf) {
    const int rb = (wm << 7) + (mf << 4) + (kq << 2);
#pragma unroll
    for (int rr = 0; rr < 4; ++rr) {
      const int row = m0 + rb + rr;
      if (FUSE) {
        u16* orow = (u16*)Out + (size_t)row * ldo;
#pragma unroll
        for (int jj = 0; jj < 2; ++jj) {
          float g = acc[mf][2 * jj][rr];
          float uu = acc[mf][2 * jj + 1][rr];
          float hv = (g / (1.f + __expf(-g))) * uu;
          orow[h0 + (wn << 5) + (jj << 4) + fr] = f2bf(hv);
        }
      } else if (F32OUT) {
        float* orow = (float*)Out + (size_t)row * ldo;
#pragma unroll
        for (int n = 0; n < 4; ++n)
          orow[n0 + (wn << 6) + (n << 4) + fr] = acc[mf][n][rr];
      } else {
        u16* orow = (u16*)Out + (size_t)row * ldo;
#pragma unroll
        for (int n = 0; n < 4; ++n)
          orow[n0 + (wn << 6) + (n << 4) + fr] = f2bf(acc[mf][n][rr]);
      }
    }
  }
#undef STG_A
#undef STG_B
#undef LDA_
#undef LDB_
#undef MFMA16
}

// ---------------- combine: out[tok] += w0*p[slot0] + w1*p[slot1] ----------------
__global__ __launch_bounds__(256) void combine_kernel(
    float* __restrict__ out, const u16* __restrict__ p_rt,
    const int* __restrict__ slot_of, const float* __restrict__ tok_w) {
  int tok = blockIdx.x;
  int j = threadIdx.x;               // 256 threads x 8 cols = 2048
  int s0 = slot_of[2 * tok], s1 = slot_of[2 * tok + 1];
  float w0 = tok_w[2 * tok], w1 = tok_w[2 * tok + 1];
  const u16* r0 = p_rt + (size_t)s0 * C_DIM + j * 8;
  const u16* r1 = p_rt + (size_t)s1 * C_DIM + j * 8;
  float* o = out + (size_t)tok * C_DIM + j * 8;
  union { uint4 v; u16 s[8]; } P0, P1;
  P0.v = *(const uint4*)r0;
  P1.v = *(const uint4*)r1;
  float4 o0 = *(const float4*)o;
  float4 o1 = *(const float4*)(o + 4);
  float r[8];
#pragma unroll
  for (int e = 0; e < 8; ++e) r[e] = w0 * bf2f(P0.s[e]) + w1 * bf2f(P1.s[e]);
  o0.x += r[0]; o0.y += r[1]; o0.z += r[2]; o0.w += r[3];
  o1.x += r[4]; o1.y += r[5]; o1.z += r[6]; o1.w += r[7];
  *(float4*)o = o0;
  *(float4*)(o + 4) = o1;
}

// ---------------- host launch ----------------
extern "C" void kernel_launch(void* const* d_in, const int* in_sizes, int n_in,
                              void* d_out, int out_size, void* d_ws, size_t ws_size,
                              hipStream_t stream) {
  const float* x   = (const float*)d_in[0];
  const float* gw  = (const float*)d_in[1];
  const float* gb  = (const float*)d_in[2];
  const float* sgw = (const float*)d_in[3];
  const float* sdw = (const float*)d_in[4];
  const float* upw = (const float*)d_in[5];
  const float* dww = (const float*)d_in[6];
  float* out = (float*)d_out;

  char* ws = (char*)d_ws;
  size_t off = 0;
  auto take = [&](size_t bytes) -> void* {
    size_t o = (off + 255) & ~(size_t)255;
    off = o + bytes;
    return (void*)(ws + o);
  };

  u16* x_bf   = (u16*)take((size_t)N_TOK * C_DIM * 2);
  u16* sgw_bf = (u16*)take((size_t)(2 * HS_DIM) * C_DIM * 2);
  u16* sdw_bf = (u16*)take((size_t)C_DIM * HS_DIM * 2);
  u16* upw_bf = (u16*)take((size_t)E_NUM * (2 * H_DIM) * C_DIM * 2);   // 92.3 MB
  u16* dww_bf = (u16*)take((size_t)E_NUM * C_DIM * H_DIM * 2);
  u16* h_sh   = (u16*)take((size_t)N_TOK * HS_DIM * 2);
  u16* h_rt   = (u16*)take((size_t)NRPAD * H_DIM * 2);                 // own buffer
  u16* p_rt   = upw_bf;  // alias: upw_bf dead after routed-up GEMM (75.5 <= 92.3 MB)

  int*   tok_e    = (int*)take((size_t)N_TOK * 2 * 4);
  float* tok_w    = (float*)take((size_t)N_TOK * 2 * 4);
  int*   slot_of  = (int*)take((size_t)N_TOK * 2 * 4);
  int*   slot_tok = (int*)take((size_t)NRPAD * 4);      // zeroed span start
  int*   counts   = (int*)take(E_NUM * 4);
  int*   cursor   = (int*)take(E_NUM * 4);
  int*   off_pad  = (int*)take(E_NUM * 4);
  int*   ntiles   = (int*)take(4);
  int*   tile_e   = (int*)take(MAXT256 * 4);
  int*   tile_s0  = (int*)take(MAXT256 * 4);
  (void)ws_size; (void)in_sizes; (void)n_in; (void)out_size;

  // zero slot_tok + counts + cursor (contiguous span)
  size_t z0 = (size_t)((char*)slot_tok - ws);
  size_t z1 = (size_t)((char*)cursor - ws) + E_NUM * 4;
  hipMemsetAsync(ws + z0, 0, z1 - z0, stream);

  // weight/activation bf16 conversion
  cvt_bf16_kernel<<<2048, 256, 0, stream>>>(x, x_bf, N_TOK * C_DIM / 4);
  cvt_bf16_kernel<<<2048, 256, 0, stream>>>(sgw, sgw_bf, 2 * HS_DIM * C_DIM / 4);
  cvt_bf16_kernel<<<2048, 256, 0, stream>>>(sdw, sdw_bf, C_DIM * HS_DIM / 4);
  cvt_bf16_kernel<<<4096, 256, 0, stream>>>(upw, upw_bf, E_NUM * 2 * H_DIM * C_DIM / 4);
  cvt_bf16_kernel<<<4096, 256, 0, stream>>>(dww, dww_bf, E_NUM * C_DIM * H_DIM / 4);

  gate_topk_kernel<<<N_TOK, 256, 0, stream>>>(x, gw, gb, tok_e, tok_w, counts);
  scan_route_kernel<<<1, 64, 0, stream>>>(counts, off_pad, tile_e, tile_s0, ntiles);
  build_slots_kernel<<<32, 256, 0, stream>>>(tok_e, off_pad, cursor, slot_tok, slot_of);

  // shared up (fused SwiGLU): h_sh = silu(x@g^T)*(x@y^T); sil rows [HS,2HS), mul [0,HS)
  gemm256<false, false, false, true><<<32 * 22, 512, 0, stream>>>(
      x_bf, sgw_bf, h_sh, HS_DIM, C_DIM, 22,
      nullptr, nullptr, nullptr, nullptr, 0, HS_DIM, 0);

  // routed up (fused SwiGLU): h_rt = silu(gather(x)@g^T)*(gather(x)@u^T)
  gemm256<true, true, false, true><<<MAXT256 * 11, 512, 0, stream>>>(
      x_bf, upw_bf, h_rt, H_DIM, C_DIM, 11,
      tile_e, tile_s0, ntiles, slot_tok, (long)(2 * H_DIM) * C_DIM, 0, H_DIM);

  // shared down: out = h_sh @ sdw^T (f32 store)
  gemm256<false, false, true, false><<<32 * 8, 512, 0, stream>>>(
      h_sh, sdw_bf, out, C_DIM, HS_DIM, 8,
      nullptr, nullptr, nullptr, nullptr, 0, 0, 0);

  // routed down: p_rt[slot] = h_rt[slot] @ dww[e]^T (bf16)
  gemm256<false, true, false, false><<<MAXT256 * 8, 512, 0, stream>>>(
      h_rt, dww_bf, p_rt, C_DIM, H_DIM, 8,
      tile_e, tile_s0, ntiles, nullptr, (long)C_DIM * H_DIM, 0, 0);

  // combine: out[tok] += w0*p_rt[slot0] + w1*p_rt[slot1]
  combine_kernel<<<N_TOK, 256, 0, stream>>>(out, p_rt, slot_of, tok_w);
}

// Round 12
// 982.308 us; speedup vs baseline: 5.4192x; 5.4192x over previous
//
#include <hip/hip_runtime.h>
#include <hip/hip_bf16.h>
#include <stdint.h>

// Problem constants (from setup_inputs)
#define N_TOK 8192
#define C_DIM 2048
#define E_NUM 8
#define H_DIM 1408
#define HS_DIM 2816
#define NRPAD 18432      // 16384 routed slots + per-expert padding to 256
#define MAXT256 72       // 64 full tiles + 8 partial

typedef unsigned short u16;
typedef float f32x4_t __attribute__((ext_vector_type(4)));
typedef short bf16x8_t __attribute__((ext_vector_type(8)));

__device__ __forceinline__ u16 f2bf(float f) {
  union { float f; uint32_t u; } c; c.f = f;
  uint32_t u = c.u;
  return (u16)((u + 0x7fffu + ((u >> 16) & 1u)) >> 16);
}
__device__ __forceinline__ float bf2f(u16 b) {
  union { uint32_t u; float f; } c; c.u = ((uint32_t)b) << 16;
  return c.f;
}

__device__ __forceinline__ void async_copy16(const u16* gsrc, u16* ldst) {
  __builtin_amdgcn_global_load_lds(
      (const __attribute__((address_space(1))) void*)gsrc,
      (__attribute__((address_space(3))) void*)ldst, 16, 0, 0);
}

#define BARRIER() asm volatile("s_barrier" ::: "memory")
#define WAITV4()  asm volatile("s_waitcnt vmcnt(4)" ::: "memory")
#define WAITV0()  asm volatile("s_waitcnt vmcnt(0)" ::: "memory")

// ---------------- fused 4-buffer fp32 -> bf16 conversion ----------------
__global__ __launch_bounds__(256) void cvt4_kernel(
    const float* __restrict__ s0, u16* __restrict__ d0, int n0,
    const float* __restrict__ s1, u16* __restrict__ d1, int n1,
    const float* __restrict__ s2, u16* __restrict__ d2, int n2,
    const float* __restrict__ s3, u16* __restrict__ d3, int n3) {
  int total = n0 + n1 + n2 + n3;
  int i = blockIdx.x * blockDim.x + threadIdx.x;
  int stride = gridDim.x * blockDim.x;
  for (; i < total; i += stride) {
    const float* src; u16* dst; int j = i;
    if (j < n0) { src = s0; dst = d0; }
    else if ((j -= n0) < n1) { src = s1; dst = d1; }
    else if ((j -= n1) < n2) { src = s2; dst = d2; }
    else { j -= n2; src = s3; dst = d3; }
    float4 v = ((const float4*)src)[j];
    ushort4 u;
    u.x = f2bf(v.x); u.y = f2bf(v.y); u.z = f2bf(v.z); u.w = f2bf(v.w);
    ((ushort4*)dst)[j] = u;
  }
}

// ---------------- gate: fp32 scores, top-2, renorm; also emits x_bf ----------
__global__ __launch_bounds__(256) void gate_topk_kernel(
    const float* __restrict__ x, const float* __restrict__ gw,
    const float* __restrict__ gbias, u16* __restrict__ x_bf,
    int* __restrict__ tok_e, float* __restrict__ tok_w, int* __restrict__ counts) {
  int n = blockIdx.x;
  const float* xr = x + (size_t)n * C_DIM;
  u16* xbr = x_bf + (size_t)n * C_DIM;
  int t = threadIdx.x;
  float acc[E_NUM];
#pragma unroll
  for (int e = 0; e < E_NUM; ++e) acc[e] = 0.f;
  for (int k0 = t * 4; k0 < C_DIM; k0 += 1024) {
    float4 xv = *(const float4*)(xr + k0);
    ushort4 xb;
    xb.x = f2bf(xv.x); xb.y = f2bf(xv.y); xb.z = f2bf(xv.z); xb.w = f2bf(xv.w);
    *(ushort4*)(xbr + k0) = xb;
#pragma unroll
    for (int e = 0; e < E_NUM; ++e) {
      float4 gv = *(const float4*)(gw + e * C_DIM + k0);
      acc[e] += xv.x * gv.x + xv.y * gv.y + xv.z * gv.z + xv.w * gv.w;
    }
  }
#pragma unroll
  for (int e = 0; e < E_NUM; ++e)
    for (int off = 32; off > 0; off >>= 1) acc[e] += __shfl_xor(acc[e], off, 64);
  __shared__ float sred[4][E_NUM];
  int wid = t >> 6, lane = t & 63;
  if (lane == 0) {
#pragma unroll
    for (int e = 0; e < E_NUM; ++e) sred[wid][e] = acc[e];
  }
  __syncthreads();
  if (t == 0) {
    float sc[E_NUM];
#pragma unroll
    for (int e = 0; e < E_NUM; ++e) {
      float s = sred[0][e] + sred[1][e] + sred[2][e] + sred[3][e];
      sc[e] = 1.f / (1.f + expf(-s));
    }
    int e0 = 0; float k0v = sc[0] + gbias[0];
    for (int e = 1; e < E_NUM; ++e) {
      float ke = sc[e] + gbias[e];
      if (ke > k0v) { k0v = ke; e0 = e; }
    }
    int e1 = -1; float k1v = -1e30f;
    for (int e = 0; e < E_NUM; ++e) {
      if (e == e0) continue;
      float ke = sc[e] + gbias[e];
      if (ke > k1v) { k1v = ke; e1 = e; }
    }
    float w0 = sc[e0], w1 = sc[e1];
    float s = w0 + w1;
    w0 /= s; w1 /= s;
    tok_e[2 * n] = e0; tok_e[2 * n + 1] = e1;
    tok_w[2 * n] = w0; tok_w[2 * n + 1] = w1;
    atomicAdd(&counts[e0], 1);
    atomicAdd(&counts[e1], 1);
  }
}

// ---------------- routing scan: 256-padded offsets + tile table ----------------
__global__ void scan_route_kernel(const int* __restrict__ counts,
                                  int* __restrict__ off_pad,
                                  int* __restrict__ tile_e, int* __restrict__ tile_s0,
                                  int* __restrict__ ntiles) {
  if (threadIdx.x == 0 && blockIdx.x == 0) {
    int off = 0, t = 0;
    for (int e = 0; e < E_NUM; ++e) {
      off_pad[e] = off;
      int tiles = (counts[e] + 255) >> 8;
      for (int i = 0; i < tiles; ++i) { tile_e[t] = e; tile_s0[t] = off + i * 256; ++t; }
      off += tiles * 256;
    }
    *ntiles = t;
  }
}

__global__ __launch_bounds__(256) void build_slots_kernel(
    const int* __restrict__ tok_e, const int* __restrict__ off_pad,
    int* __restrict__ cursor, int* __restrict__ slot_tok, int* __restrict__ slot_of) {
  int n = blockIdx.x * blockDim.x + threadIdx.x;
  if (n >= N_TOK) return;
#pragma unroll
  for (int j = 0; j < 2; ++j) {
    int e = tok_e[2 * n + j];
    int pos = atomicAdd(&cursor[e], 1);
    int s = off_pad[e] + pos;
    slot_tok[s] = n;
    slot_of[2 * n + j] = s;
  }
}

// ---------------- 256x256x64 8-phase bf16 GEMM (T2+T3+T4+T5) ----------------
// Round-8 proven schedule (8 barriers/K-tile, vmcnt(4) at P2/P4, never 0).
// FUSE: up-proj + SwiGLU: B tile rows interleave 16-row sil/mul blocks so
// acc[m][2j]=g, acc[m][2j+1]=u share a lane; epilogue writes silu(g)*u.
// COMBINE: shared-down epilogue also adds the routed-expert contributions:
// out[row] = acc + w0*p_rt[slot0[row]] + w1*p_rt[slot1[row]]  (f32 store).
template <bool GATHER, bool ROUTE, bool FUSE, bool COMBINE>
__global__ __launch_bounds__(512, 2) void gemm256(
    const u16* __restrict__ A, const u16* __restrict__ B,
    void* __restrict__ Out, int ldo, int K, int nbn,
    const int* __restrict__ tile_e, const int* __restrict__ tile_s0,
    const int* __restrict__ ntiles, const int* __restrict__ slot_tok,
    long estride, int silbase, int mulbase,
    const int* __restrict__ slot_of, const float* __restrict__ tok_w,
    const u16* __restrict__ p_rt) {
  // XCD-contiguous chunks; within a chunk, 4-mt bands swept across nt.
  const int chunk = gridDim.x >> 3;
  const int orig = blockIdx.x;
  const int l = (orig & 7) * chunk + (orig >> 3);
  const int bandsz = nbn << 2;
  const int band = l / bandsz;
  const int rem = l - band * bandsz;
  const int nt = rem >> 2;
  const int mt = (band << 2) + (rem & 3);
  if (ROUTE) { if (mt >= *ntiles) return; }
  const int m0 = ROUTE ? tile_s0[mt] : (mt << 8);
  const u16* Bb = B + (ROUTE ? (size_t)tile_e[mt] * (size_t)estride : 0);
  const int n0 = nt << 8;   // acc-col base (unfused)
  const int h0 = nt << 7;   // fused h-col base

  __shared__ u16 lds[65536];   // [buf(2)][mat(2)][ks(2)][256][32]

  const int t = threadIdx.x;
  const int w = t >> 6, lane = t & 63;
  const int wst = w << 9;                  // wave LDS slice within an issue
  // staging source pointers (pre-swizzled global col-group)
  const int rt2 = t >> 2;                  // staged row 0..127
  const int coff = (((t & 3) ^ ((rt2 >> 1) & 3)) << 3);
  const u16* aS[2]; const u16* bS[2];
#pragma unroll
  for (int j = 0; j < 2; ++j) {
    int r = (j << 7) + rt2;
    int arow = GATHER ? slot_tok[m0 + r] : (m0 + r);
    aS[j] = A + (size_t)arow * K + coff;
    int grow;
    if (FUSE) {
      // tile B-row r -> weight row: blk=r>>4 (even: sil, odd: mul)
      grow = (((r >> 4) & 1) ? mulbase : silbase) + h0 + ((r >> 5) << 4) + (r & 15);
    } else {
      grow = n0 + r;
    }
    bS[j] = Bb + (size_t)grow * K + coff;
  }

  const int wm = w >> 2, wn = w & 3;
  const int fr = lane & 15, kq = lane >> 4;
  const int swz = ((kq ^ ((fr >> 1) & 3)) << 3);   // u16 col offset in 32-u16 row

  f32x4_t acc[8][4];
  f32x4_t zero4 = {0.f, 0.f, 0.f, 0.f};
#pragma unroll
  for (int m = 0; m < 8; ++m)
#pragma unroll
    for (int n = 0; n < 4; ++n) acc[m][n] = zero4;

#define STG_A(KS) \
  async_copy16(aS[0] + kst + (KS)*32, &lds[nxtb + (KS)*8192 + wst]); \
  async_copy16(aS[1] + kst + (KS)*32, &lds[nxtb + (KS)*8192 + 4096 + wst]);
#define STG_B(KS) \
  async_copy16(bS[0] + kst + (KS)*32, &lds[nxtb + 16384 + (KS)*8192 + wst]); \
  async_copy16(bS[1] + kst + (KS)*32, &lds[nxtb + 16384 + (KS)*8192 + 4096 + wst]);
#define LDA(QM, KS) \
  _Pragma("unroll") \
  for (int m = 0; m < 4; ++m) { \
    int row = (wm << 7) + (QM)*64 + (m << 4) + fr; \
    afr[m] = *(const bf16x8_t*)&lds[cur + (KS)*8192 + (row << 5) + swz]; \
  }
#define LDB(KS) \
  _Pragma("unroll") \
  for (int n = 0; n < 4; ++n) { \
    int row = (wn << 6) + (n << 4) + fr; \
    bfr[n] = *(const bf16x8_t*)&lds[cur + 16384 + (KS)*8192 + (row << 5) + swz]; \
  }
#define MFMA16(QM) \
  __builtin_amdgcn_s_setprio(1); \
  _Pragma("unroll") \
  for (int m = 0; m < 4; ++m) \
    _Pragma("unroll") \
    for (int n = 0; n < 4; ++n) \
      acc[(QM)*4 + m][n] = __builtin_amdgcn_mfma_f32_16x16x32_bf16( \
          afr[m], bfr[n], acc[(QM)*4 + m][n], 0, 0, 0); \
  __builtin_amdgcn_s_setprio(0);

  const int KT = K >> 6;
  // prologue: stage K-tile 0 into buf0 (order A0,B0,A1,B1), wait first 2 HTs
  {
    const int nxtb = 0, kst = 0;
    STG_A(0); STG_B(0); STG_A(1); STG_B(1);
  }
  WAITV4();
  BARRIER();

  for (int kt = 0; kt < KT; ++kt) {
    const int cur = (kt & 1) << 15;
    const int nxtb = ((kt + 1) & 1) << 15;
    const int kst = (kt + 1 < KT ? kt + 1 : kt) << 6;   // last tile: junk re-stage
    bf16x8_t afr[4], bfr[4];

    // phase 1: (qm0, ks0); stage A-ks0 of next
    LDB(0); LDA(0, 0); STG_A(0);
    BARRIER();
    MFMA16(0);
    BARRIER();
    // phase 2: (qm1, ks0); stage B-ks0
    LDA(1, 0); STG_B(0);
    BARRIER();
    MFMA16(1);
    WAITV4();        // A1(kt),B1(kt) landed; A0/B0(kt+1) may fly
    BARRIER();
    // phase 3: (qm0, ks1); stage A-ks1
    LDB(1); LDA(0, 1); STG_A(1);
    BARRIER();
    MFMA16(0);
    BARRIER();
    // phase 4: (qm1, ks1); stage B-ks1
    LDA(1, 1); STG_B(1);
    BARRIER();
    MFMA16(1);
    WAITV4();        // A0(kt+1),B0(kt+1) landed; A1/B1(kt+1) may fly
    BARRIER();
  }
  WAITV0();          // drain junk stages before LDS dealloc

  // epilogue
#pragma unroll
  for (int mf = 0; mf < 8; ++mf) {
    const int rb = (wm << 7) + (mf << 4) + (kq << 2);
#pragma unroll
    for (int rr = 0; rr < 4; ++rr) {
      const int row = m0 + rb + rr;
      if (FUSE) {
        u16* orow = (u16*)Out + (size_t)row * ldo;
#pragma unroll
        for (int jj = 0; jj < 2; ++jj) {
          float g = acc[mf][2 * jj][rr];
          float uu = acc[mf][2 * jj + 1][rr];
          float hv = (g / (1.f + __expf(-g))) * uu;
          orow[h0 + (wn << 5) + (jj << 4) + fr] = f2bf(hv);
        }
      } else if (COMBINE) {
        float* orow = (float*)Out + (size_t)row * ldo;
        int s0 = slot_of[2 * row], s1 = slot_of[2 * row + 1];
        float w0 = tok_w[2 * row], w1 = tok_w[2 * row + 1];
        const u16* pr0 = p_rt + (size_t)s0 * C_DIM;
        const u16* pr1 = p_rt + (size_t)s1 * C_DIM;
#pragma unroll
        for (int n = 0; n < 4; ++n) {
          int col = n0 + (wn << 6) + (n << 4) + fr;
          orow[col] = acc[mf][n][rr] + w0 * bf2f(pr0[col]) + w1 * bf2f(pr1[col]);
        }
      } else {
        u16* orow = (u16*)Out + (size_t)row * ldo;
#pragma unroll
        for (int n = 0; n < 4; ++n) {
          int col = n0 + (wn << 6) + (n << 4) + fr;
          orow[col] = f2bf(acc[mf][n][rr]);
        }
      }
    }
  }
#undef STG_A
#undef STG_B
#undef LDA
#undef LDB
#undef MFMA16
}

// ---------------- host launch ----------------
extern "C" void kernel_launch(void* const* d_in, const int* in_sizes, int n_in,
                              void* d_out, int out_size, void* d_ws, size_t ws_size,
                              hipStream_t stream) {
  const float* x   = (const float*)d_in[0];
  const float* gw  = (const float*)d_in[1];
  const float* gb  = (const float*)d_in[2];
  const float* sgw = (const float*)d_in[3];
  const float* sdw = (const float*)d_in[4];
  const float* upw = (const float*)d_in[5];
  const float* dww = (const float*)d_in[6];
  float* out = (float*)d_out;

  char* ws = (char*)d_ws;
  size_t off = 0;
  auto take = [&](size_t bytes) -> void* {
    size_t o = (off + 255) & ~(size_t)255;
    off = o + bytes;
    return (void*)(ws + o);
  };

  u16* x_bf   = (u16*)take((size_t)N_TOK * C_DIM * 2);
  u16* sgw_bf = (u16*)take((size_t)(2 * HS_DIM) * C_DIM * 2);
  u16* sdw_bf = (u16*)take((size_t)C_DIM * HS_DIM * 2);
  u16* upw_bf = (u16*)take((size_t)E_NUM * (2 * H_DIM) * C_DIM * 2);   // 92.3 MB
  u16* dww_bf = (u16*)take((size_t)E_NUM * C_DIM * H_DIM * 2);
  u16* h_sh   = (u16*)take((size_t)N_TOK * HS_DIM * 2);
  u16* h_rt   = (u16*)take((size_t)NRPAD * H_DIM * 2);                 // own buffer
  u16* p_rt   = upw_bf;  // alias: upw_bf dead after routed-up GEMM (75.5 <= 92.3 MB)

  int*   tok_e    = (int*)take((size_t)N_TOK * 2 * 4);
  float* tok_w    = (float*)take((size_t)N_TOK * 2 * 4);
  int*   slot_of  = (int*)take((size_t)N_TOK * 2 * 4);
  int*   slot_tok = (int*)take((size_t)NRPAD * 4);      // zeroed span start
  int*   counts   = (int*)take(E_NUM * 4);
  int*   cursor   = (int*)take(E_NUM * 4);
  int*   off_pad  = (int*)take(E_NUM * 4);
  int*   ntiles   = (int*)take(4);
  int*   tile_e   = (int*)take(MAXT256 * 4);
  int*   tile_s0  = (int*)take(MAXT256 * 4);
  (void)ws_size; (void)in_sizes; (void)n_in; (void)out_size;

  // zero slot_tok + counts + cursor (contiguous span)
  size_t z0 = (size_t)((char*)slot_tok - ws);
  size_t z1 = (size_t)((char*)cursor - ws) + E_NUM * 4;
  hipMemsetAsync(ws + z0, 0, z1 - z0, stream);

  // weight bf16 conversion (single fused launch; x converts inside gate)
  cvt4_kernel<<<4096, 256, 0, stream>>>(
      sgw, sgw_bf, 2 * HS_DIM * C_DIM / 4,
      sdw, sdw_bf, C_DIM * HS_DIM / 4,
      upw, upw_bf, E_NUM * 2 * H_DIM * C_DIM / 4,
      dww, dww_bf, E_NUM * C_DIM * H_DIM / 4);

  gate_topk_kernel<<<N_TOK, 256, 0, stream>>>(x, gw, gb, x_bf, tok_e, tok_w, counts);
  scan_route_kernel<<<1, 64, 0, stream>>>(counts, off_pad, tile_e, tile_s0, ntiles);
  build_slots_kernel<<<32, 256, 0, stream>>>(tok_e, off_pad, cursor, slot_tok, slot_of);

  // shared up (fused SwiGLU): h_sh = silu(x@g^T)*(x@y^T); sil rows [HS,2HS), mul [0,HS)
  gemm256<false, false, true, false><<<32 * 22, 512, 0, stream>>>(
      x_bf, sgw_bf, h_sh, HS_DIM, C_DIM, 22,
      nullptr, nullptr, nullptr, nullptr, 0, HS_DIM, 0,
      nullptr, nullptr, nullptr);

  // routed up (fused SwiGLU): h_rt = silu(gather(x)@g^T)*(gather(x)@u^T)
  gemm256<true, true, true, false><<<MAXT256 * 11, 512, 0, stream>>>(
      x_bf, upw_bf, h_rt, H_DIM, C_DIM, 11,
      tile_e, tile_s0, ntiles, slot_tok, (long)(2 * H_DIM) * C_DIM, 0, H_DIM,
      nullptr, nullptr, nullptr);

  // routed down: p_rt[slot] = h_rt[slot] @ dww[e]^T (bf16)
  gemm256<false, true, false, false><<<MAXT256 * 8, 512, 0, stream>>>(
      h_rt, dww_bf, p_rt, C_DIM, H_DIM, 8,
      tile_e, tile_s0, ntiles, nullptr, (long)C_DIM * H_DIM, 0, 0,
      nullptr, nullptr, nullptr);

  // shared down + combine: out = h_sh @ sdw^T + w0*p_rt[s0] + w1*p_rt[s1]
  gemm256<false, false, false, true><<<32 * 8, 512, 0, stream>>>(
      h_sh, sdw_bf, out, C_DIM, HS_DIM, 8,
      nullptr, nullptr, nullptr, nullptr, 0, 0, 0,
      slot_of, tok_w, p_rt);
}